// Round 4
// baseline (489.147 us; speedup 1.0000x reference)
//
#include <hip/hip_runtime.h>
#include <math.h>

#define N_SRC   200000
#define N_DST   50000
#define N_EDGES 800000
#define N_IN    256
#define N_OUT   128
#define CAP     64        // padded-CSR slots/row; P(deg>64 | Binom(800K,1/50K)) ~ 1e-18/row

// ---- workspace layout (bytes), all 16B-aligned ----
#define WS_CNT   0            // int[50000] (+pad)
#define WS_WTW   204800       // ushort[128*256] bf16 (W_w^T)
#define WS_WTB   270336       // ushort[128*256] bf16 (W_b^T)
#define WS_SELF  335872       // ushort[50000*128] bf16
#define WS_Y     13135872     // ushort[200000*128] bf16
#define WS_CSR   64335872     // int2[50000*64]
// total ~90 MB

typedef short  bf16x8 __attribute__((ext_vector_type(8)));
typedef unsigned short u16x8 __attribute__((ext_vector_type(8)));
typedef float  f32x4  __attribute__((ext_vector_type(4)));

__device__ inline unsigned short f2bf(float f) {
    unsigned u = __builtin_bit_cast(unsigned, f);
    u += 0x7fffu + ((u >> 16) & 1u);           // RNE
    return (unsigned short)(u >> 16);
}
__device__ inline float bf2f(unsigned short h) {
    return __builtin_bit_cast(float, (unsigned)h << 16);
}

// ---------------- init: weight transpose+bf16, zero cnt ----------------
// 256 blocks x 256 threads = 65536 = 2*128*256
__global__ __launch_bounds__(256) void k_init(const float* __restrict__ Ww,
                                              const float* __restrict__ Wb,
                                              unsigned short* __restrict__ Wtw,
                                              unsigned short* __restrict__ Wtb,
                                              int* __restrict__ cnt) {
    int tot = blockIdx.x * 256 + threadIdx.x;
    int sel = tot >> 15;
    int idx = tot & 32767;
    int n = idx >> 8, k = idx & 255;
    const float* src = sel ? Wb : Ww;
    unsigned short* dst = sel ? Wtb : Wtw;
    dst[n * 256 + k] = f2bf(src[k * 128 + n]);
    if (tot < N_DST) cnt[tot] = 0;
}

// ---------------- mega: scatter (padded CSR) + both MFMA GEMMs ----------------
// blocks [0,3125): scatter 800000 edges
// blocks [3125,6250): y = x @ W_w           (200000 rows)
// blocks [6250,7032): self = x[sn] @ W_b    (50000 rows)
//
// BARRIER-FREE K-loop: each lane loads its own MFMA fragments directly from
// global (A: 32 B f32 per tile, per wave = 16 rows x 128 B contiguous;
// B: 8x16 B from the 64 KB L2-resident weight matrix). No LDS staging, no
// per-tile vmcnt(0)+barrier drain -> compiler can pipeline loads across all
// 8 k-tiles. LDS kept only for the write-coalescing epilogue.
#define GSCAT 3125
#define GBIG  3125
#define GSELF 782
#define EPS 132         // epilogue LDS stride

__global__ __launch_bounds__(256, 4) void k_mega(
        const float* __restrict__ x,
        const int* __restrict__ erows, const int* __restrict__ ecols,
        const float* __restrict__ evals, const int* __restrict__ sn,
        const unsigned short* __restrict__ Wtw, const unsigned short* __restrict__ Wtb,
        int* __restrict__ cnt, int2* __restrict__ csr_pad,
        unsigned short* __restrict__ ybuf, unsigned short* __restrict__ selfp) {
    __shared__ __align__(16) unsigned short sm[64 * EPS];   // 16896 B, epilogue only
    const int tid = threadIdx.x;

    if (blockIdx.x < GSCAT) {
        int i = blockIdx.x * 256 + tid;          // 3125*256 == 800000 exactly
        int r = erows[i];
        int rank = atomicAdd(&cnt[r], 1);
        if (rank < CAP) {
            int2 cv;
            cv.x = ecols[i];
            cv.y = __builtin_bit_cast(int, evals[i]);
            csr_pad[r * CAP + rank] = cv;
        }
        return;
    }

    const int gb = blockIdx.x - GSCAT;
    const bool isBig = gb < GBIG;
    const int* rowidx = isBig ? nullptr : sn;
    const unsigned short* Bt = isBig ? Wtw : Wtb;
    unsigned short* Y = isBig ? ybuf : selfp;
    const int M = isBig ? N_SRC : N_DST;
    const int bid = isBig ? gb : gb - GBIG;

    const int lane = tid & 63, wid = tid >> 6;
    const int l15 = lane & 15, quad = lane >> 4;
    const int row0 = bid * 64;

    // per-lane A row (this lane's own MFMA fragment row)
    int srow = row0 + wid * 16 + l15;
    if (srow >= M) srow = M - 1;
    if (rowidx) srow = rowidx[srow];
    const float*          ap = x  + (long)srow * 256 + quad * 8;
    const unsigned short* bp = Bt + (long)l15 * 256 + quad * 8;

    f32x4 acc[8];
    #pragma unroll
    for (int t = 0; t < 8; t++) acc[t] = (f32x4){0.f, 0.f, 0.f, 0.f};

    #pragma unroll
    for (int kt = 0; kt < 8; kt++) {
        const int k0 = kt * 32;
        // A fragment: 8 f32 -> bf16x8 (row srow, k = k0 + quad*8 .. +8)
        float4 a0 = *(const float4*)(ap + k0);
        float4 a1 = *(const float4*)(ap + k0 + 4);
        // B fragments: 8 x 16 B (rows t*16+l15, k = k0 + quad*8 .. +8), L2-hit
        bf16x8 bfr[8];
        #pragma unroll
        for (int t = 0; t < 8; t++)
            bfr[t] = *(const bf16x8*)(bp + (long)t * 4096 + k0);
        bf16x8 af;
        af[0] = (short)f2bf(a0.x); af[1] = (short)f2bf(a0.y);
        af[2] = (short)f2bf(a0.z); af[3] = (short)f2bf(a0.w);
        af[4] = (short)f2bf(a1.x); af[5] = (short)f2bf(a1.y);
        af[6] = (short)f2bf(a1.z); af[7] = (short)f2bf(a1.w);
        #pragma unroll
        for (int t = 0; t < 8; t++)
            acc[t] = __builtin_amdgcn_mfma_f32_16x16x32_bf16(af, bfr[t], acc[t], 0, 0, 0);
    }

    // epilogue: acc -> LDS -> coalesced 64 B/thread global writes
    #pragma unroll
    for (int t = 0; t < 8; t++)
        #pragma unroll
        for (int rg = 0; rg < 4; rg++)
            sm[(wid * 16 + quad * 4 + rg) * EPS + t * 16 + l15] = f2bf(acc[t][rg]);
    __syncthreads();
    const int orow = tid >> 2, oc0 = (tid & 3) * 32;
    if (row0 + orow < M) {
        unsigned short* dst = Y + (long)(row0 + orow) * 128 + oc0;
        #pragma unroll
        for (int i = 0; i < 4; i++)
            *(u16x8*)(dst + i * 8) = *(const u16x8*)&sm[orow * EPS + oc0 + i * 8];
    }
}

// ---------------- fused SpMM + bias + ELU + layernorm + affine ----------------
// 4 waves/block, one dst row per wave; row's <=64 edges load in ONE int2/lane.
// Gather loop runs 8-deep: 8 independent 256 B row-gathers in flight per group.
// Zero-padded CSR slots (c=0, v=0) make over-issue safe: fmaf adds 0.
#define GATHER(j) \
    int   c##j = __shfl(cv.x, e0 + j, 64); \
    float v##j = __builtin_bit_cast(float, __shfl(cv.y, e0 + j, 64)); \
    unsigned p##j = *(const unsigned*)(y + (long)c##j * 128 + (lane << 1));
#define ACCUM(j) \
    a0 = fmaf(v##j, __builtin_bit_cast(float, p##j << 16), a0); \
    a1 = fmaf(v##j, __builtin_bit_cast(float, p##j & 0xffff0000u), a1);

__global__ __launch_bounds__(256) void k_sage(const unsigned short* __restrict__ y,
                                              const unsigned short* __restrict__ selfp,
                                              const int* __restrict__ cnt,
                                              const int2* __restrict__ csr_pad,
                                              const float* __restrict__ bw,
                                              const float* __restrict__ bb,
                                              const float* __restrict__ scale,
                                              const float* __restrict__ offs,
                                              float* __restrict__ out) {
    const int tid = threadIdx.x, lane = tid & 63, wid = tid >> 6;
    const int row = blockIdx.x * 4 + wid;
    const int m = min(cnt[row], CAP);

    // coalesced edge batch: one int2 per lane (zero-filled beyond m)
    int2 cv = (lane < m) ? csr_pad[(long)row * CAP + lane] : make_int2(0, 0);

    // self half (cols 0..127)
    unsigned spk = *(const unsigned*)(selfp + (long)row * 128 + lane * 2);
    float s0 = bf2f((unsigned short)(spk & 0xffff)) + bb[lane * 2];
    float s1 = bf2f((unsigned short)(spk >> 16))    + bb[lane * 2 + 1];
    s0 = s0 > 0.f ? s0 : expm1f(s0);
    s1 = s1 > 0.f ? s1 : expm1f(s1);

    // neigh half (cols 128..255): 8-deep pipelined gather
    float a0 = 0.f, a1 = 0.f;
    const int mm = (m + 7) & ~7;
    for (int e0 = 0; e0 < mm; e0 += 8) {
        GATHER(0) GATHER(1) GATHER(2) GATHER(3)
        GATHER(4) GATHER(5) GATHER(6) GATHER(7)
        ACCUM(0) ACCUM(1) ACCUM(2) ACCUM(3)
        ACCUM(4) ACCUM(5) ACCUM(6) ACCUM(7)
    }
    a0 += bw[lane * 2];
    a1 += bw[lane * 2 + 1];
    a0 = a0 > 0.f ? a0 : expm1f(a0);
    a1 = a1 > 0.f ? a1 : expm1f(a1);

    // layernorm over 256 values (4 per lane)
    float s  = s0 + s1 + a0 + a1;
    float s2 = s0 * s0 + s1 * s1 + a0 * a0 + a1 * a1;
    #pragma unroll
    for (int o = 32; o > 0; o >>= 1) {
        s  += __shfl_xor(s,  o, 64);
        s2 += __shfl_xor(s2, o, 64);
    }
    float mean = s * (1.f / 256.f);
    float var  = s2 * (1.f / 256.f) - mean * mean;
    float rstd = rsqrtf(var + 1e-9f);

    float* orow = out + (long)row * 256;
    float2 w0, w1;
    w0.x = (s0 - mean) * rstd * scale[lane * 2]           + offs[lane * 2];
    w0.y = (s1 - mean) * rstd * scale[lane * 2 + 1]       + offs[lane * 2 + 1];
    w1.x = (a0 - mean) * rstd * scale[128 + lane * 2]     + offs[128 + lane * 2];
    w1.y = (a1 - mean) * rstd * scale[128 + lane * 2 + 1] + offs[128 + lane * 2 + 1];
    *(float2*)(orow + lane * 2)       = w0;
    *(float2*)(orow + 128 + lane * 2) = w1;
}

extern "C" void kernel_launch(void* const* d_in, const int* in_sizes, int n_in,
                              void* d_out, int out_size, void* d_ws, size_t ws_size,
                              hipStream_t stream) {
    const float* x     = (const float*)d_in[0];
    const int*   erows = (const int*)  d_in[1];
    const int*   ecols = (const int*)  d_in[2];
    const float* evals = (const float*)d_in[3];
    const int*   sn    = (const int*)  d_in[4];
    const float* Ww    = (const float*)d_in[5];
    const float* bw    = (const float*)d_in[6];
    const float* Wb    = (const float*)d_in[7];
    const float* bb    = (const float*)d_in[8];
    const float* scale = (const float*)d_in[9];
    const float* offs  = (const float*)d_in[10];
    float* out = (float*)d_out;

    char* ws = (char*)d_ws;
    int*   cnt     = (int*)  (ws + WS_CNT);
    unsigned short* Wtw   = (unsigned short*)(ws + WS_WTW);
    unsigned short* Wtb   = (unsigned short*)(ws + WS_WTB);
    unsigned short* selfp = (unsigned short*)(ws + WS_SELF);
    unsigned short* ybuf  = (unsigned short*)(ws + WS_Y);
    int2*  csr_pad = (int2*) (ws + WS_CSR);

    k_init <<<256, 256, 0, stream>>>(Ww, Wb, Wtw, Wtb, cnt);
    k_mega <<<GSCAT + GBIG + GSELF, 256, 0, stream>>>(x, erows, ecols, evals, sn,
                                                      Wtw, Wtb, cnt, csr_pad, ybuf, selfp);
    k_sage <<<N_DST / 4, 256, 0, stream>>>(ybuf, selfp, cnt, csr_pad,
                                           bw, bb, scale, offs, out);
}

// Round 5
// 414.401 us; speedup vs baseline: 1.1804x; 1.1804x over previous
//
#include <hip/hip_runtime.h>
#include <math.h>

#define N_SRC   200000
#define N_DST   50000
#define N_EDGES 800000
#define N_IN    256
#define N_OUT   128
#define CAP     64        // padded-CSR slots/row; P(deg>64 | Binom(800K,1/50K)) ~ 1e-18/row

// ---- workspace layout (bytes), all 16B-aligned ----
#define WS_CNT   0            // int[50000] (+pad)
#define WS_WTW   204800       // ushort[128*256] bf16 (W_w^T)
#define WS_WTB   270336       // ushort[128*256] bf16 (W_b^T)
#define WS_SELF  335872       // ushort[50000*128] bf16
#define WS_Y     13135872     // ushort[200000*128] bf16
#define WS_CSR   64335872     // int2[50000*64]
// total ~90 MB

typedef short  bf16x8 __attribute__((ext_vector_type(8)));
typedef unsigned short u16x8 __attribute__((ext_vector_type(8)));
typedef float  f32x4  __attribute__((ext_vector_type(4)));

__device__ inline unsigned short f2bf(float f) {
    unsigned u = __builtin_bit_cast(unsigned, f);
    u += 0x7fffu + ((u >> 16) & 1u);           // RNE
    return (unsigned short)(u >> 16);
}
__device__ inline float bf2f(unsigned short h) {
    return __builtin_bit_cast(float, (unsigned)h << 16);
}

// ---------------- init: weight transpose+bf16, zero cnt ----------------
// 256 blocks x 256 threads = 65536 = 2*128*256
__global__ __launch_bounds__(256) void k_init(const float* __restrict__ Ww,
                                              const float* __restrict__ Wb,
                                              unsigned short* __restrict__ Wtw,
                                              unsigned short* __restrict__ Wtb,
                                              int* __restrict__ cnt) {
    int tot = blockIdx.x * 256 + threadIdx.x;
    int sel = tot >> 15;
    int idx = tot & 32767;
    int n = idx >> 8, k = idx & 255;
    const float* src = sel ? Wb : Ww;
    unsigned short* dst = sel ? Wtb : Wtw;
    dst[n * 256 + k] = f2bf(src[k * 128 + n]);
    if (tot < N_DST) cnt[tot] = 0;
}

// ---------------- mega: scatter (padded CSR) + both MFMA GEMMs ----------------
// blocks [0,3125): scatter 800000 edges
// blocks [3125,6250): y = x @ W_w           (200000 rows)
// blocks [6250,7032): self = x[sn] @ W_b    (50000 rows)
//
// Structure: whole 64 KB W^T staged into LDS ONCE per block (XOR-swizzled vs
// the row-stride-512B bank conflict), all 16 A-fragment loads (8 k-tiles)
// issued up front into named registers with sched_barrier(0) pinning their
// issue before any consumer. K-loop is barrier-free: convert + swizzled
// ds_read + MFMA only. One latency drain per block instead of 8.
#define GSCAT 3125
#define GBIG  3125
#define GSELF 782
#define EPS 132         // epilogue LDS stride (ushorts)

// swizzled LDS ushort index for B: row (0..127), chunk (0..31) of 8 bf16
#define BSWZ(row, chunk) ((row) * 256 + (((chunk) ^ ((row) & 7)) << 3))

__global__ __launch_bounds__(256, 2) void k_mega(
        const float* __restrict__ x,
        const int* __restrict__ erows, const int* __restrict__ ecols,
        const float* __restrict__ evals, const int* __restrict__ sn,
        const unsigned short* __restrict__ Wtw, const unsigned short* __restrict__ Wtb,
        int* __restrict__ cnt, int2* __restrict__ csr_pad,
        unsigned short* __restrict__ ybuf, unsigned short* __restrict__ selfp) {
    // 64 KB: swizzled B (128 rows x 256 ush); reused for the epilogue transpose
    __shared__ __align__(16) unsigned short sm[32768];
    const int tid = threadIdx.x;

    if (blockIdx.x < GSCAT) {
        int i = blockIdx.x * 256 + tid;          // 3125*256 == 800000 exactly
        int r = erows[i];
        int rank = atomicAdd(&cnt[r], 1);
        if (rank < CAP) {
            int2 cv;
            cv.x = ecols[i];
            cv.y = __builtin_bit_cast(int, evals[i]);
            csr_pad[r * CAP + rank] = cv;
        }
        return;
    }

    const int gb = blockIdx.x - GSCAT;
    const bool isBig = gb < GBIG;
    const int* rowidx = isBig ? nullptr : sn;
    const unsigned short* Bt = isBig ? Wtw : Wtb;
    unsigned short* Y = isBig ? ybuf : selfp;
    const int M = isBig ? N_SRC : N_DST;
    const int bid = isBig ? gb : gb - GBIG;

    const int lane = tid & 63, wid = tid >> 6;
    const int l15 = lane & 15, quad = lane >> 4;
    const int row0 = bid * 64;

    // per-lane A row (this lane's own MFMA fragment row)
    int srow = row0 + wid * 16 + l15;
    if (srow >= M) srow = M - 1;
    if (rowidx) srow = rowidx[srow];
    const float* ap = x + (long)srow * 256 + quad * 8;

    f32x4 acc[8];
    #pragma unroll
    for (int t = 0; t < 8; t++) acc[t] = (f32x4){0.f, 0.f, 0.f, 0.f};

    // ---- issue phase: B half 1 (linear, coalesced) + ALL A fragments ----
    u16x8 bst[8];
    #pragma unroll
    for (int j = 0; j < 8; j++)
        bst[j] = ((const u16x8*)Bt)[j * 256 + tid];
    float4 areg[16];
    #pragma unroll
    for (int kt = 0; kt < 8; kt++) {
        areg[2 * kt]     = *(const float4*)(ap + kt * 32);
        areg[2 * kt + 1] = *(const float4*)(ap + kt * 32 + 4);
    }
    __builtin_amdgcn_sched_barrier(0);   // pin all load issues before consumers

    // ---- stage B half 1 (waits only its own 8 loads; A stays in flight) ----
    #pragma unroll
    for (int j = 0; j < 8; j++) {
        int slot = j * 256 + tid;
        *(u16x8*)&sm[BSWZ(slot >> 5, slot & 31)] = bst[j];
    }
    // ---- issue + stage B half 2 ----
    #pragma unroll
    for (int j = 0; j < 8; j++)
        bst[j] = ((const u16x8*)Bt)[(j + 8) * 256 + tid];
    __builtin_amdgcn_sched_barrier(0);
    #pragma unroll
    for (int j = 0; j < 8; j++) {
        int slot = (j + 8) * 256 + tid;
        *(u16x8*)&sm[BSWZ(slot >> 5, slot & 31)] = bst[j];
    }
    __syncthreads();   // single drain point per block

    // ---- barrier-free K loop: 8 k-tiles x 8 n-tiles ----
    #pragma unroll
    for (int kt = 0; kt < 8; kt++) {
        float4 a0 = areg[2 * kt], a1 = areg[2 * kt + 1];
        bf16x8 af;
        af[0] = (short)f2bf(a0.x); af[1] = (short)f2bf(a0.y);
        af[2] = (short)f2bf(a0.z); af[3] = (short)f2bf(a0.w);
        af[4] = (short)f2bf(a1.x); af[5] = (short)f2bf(a1.y);
        af[6] = (short)f2bf(a1.z); af[7] = (short)f2bf(a1.w);
        const int chunk = kt * 4 + quad;
        #pragma unroll
        for (int t = 0; t < 8; t++) {
            const int row = t * 16 + l15;
            bf16x8 bfv = *(const bf16x8*)&sm[BSWZ(row, chunk)];
            acc[t] = __builtin_amdgcn_mfma_f32_16x16x32_bf16(af, bfv, acc[t], 0, 0, 0);
        }
    }

    // ---- epilogue: acc -> LDS (reuse sm) -> coalesced 64 B/thread writes ----
    __syncthreads();   // all waves done reading B before overwrite
    #pragma unroll
    for (int t = 0; t < 8; t++)
        #pragma unroll
        for (int rg = 0; rg < 4; rg++)
            sm[(wid * 16 + quad * 4 + rg) * EPS + t * 16 + l15] = f2bf(acc[t][rg]);
    __syncthreads();
    const int orow = tid >> 2, oc0 = (tid & 3) * 32;
    if (row0 + orow < M) {
        unsigned short* dst = Y + (long)(row0 + orow) * 128 + oc0;
        #pragma unroll
        for (int i = 0; i < 4; i++)
            *(u16x8*)(dst + i * 8) = *(const u16x8*)&sm[orow * EPS + oc0 + i * 8];
    }
}

// ---------------- fused SpMM + bias + ELU + layernorm + affine ----------------
// 4 waves/block, one dst row per wave; row's <=64 edges load in ONE int2/lane.
// Gather loop runs 8-deep: 8 independent 256 B row-gathers in flight per group.
// Zero-padded CSR slots (c=0, v=0) make over-issue safe: fmaf adds 0.
#define GATHER(j) \
    int   c##j = __shfl(cv.x, e0 + j, 64); \
    float v##j = __builtin_bit_cast(float, __shfl(cv.y, e0 + j, 64)); \
    unsigned p##j = *(const unsigned*)(y + (long)c##j * 128 + (lane << 1));
#define ACCUM(j) \
    a0 = fmaf(v##j, __builtin_bit_cast(float, p##j << 16), a0); \
    a1 = fmaf(v##j, __builtin_bit_cast(float, p##j & 0xffff0000u), a1);

__global__ __launch_bounds__(256) void k_sage(const unsigned short* __restrict__ y,
                                              const unsigned short* __restrict__ selfp,
                                              const int* __restrict__ cnt,
                                              const int2* __restrict__ csr_pad,
                                              const float* __restrict__ bw,
                                              const float* __restrict__ bb,
                                              const float* __restrict__ scale,
                                              const float* __restrict__ offs,
                                              float* __restrict__ out) {
    const int tid = threadIdx.x, lane = tid & 63, wid = tid >> 6;
    const int row = blockIdx.x * 4 + wid;
    const int m = min(cnt[row], CAP);

    // coalesced edge batch: one int2 per lane (zero-filled beyond m)
    int2 cv = (lane < m) ? csr_pad[(long)row * CAP + lane] : make_int2(0, 0);

    // self half (cols 0..127)
    unsigned spk = *(const unsigned*)(selfp + (long)row * 128 + lane * 2);
    float s0 = bf2f((unsigned short)(spk & 0xffff)) + bb[lane * 2];
    float s1 = bf2f((unsigned short)(spk >> 16))    + bb[lane * 2 + 1];
    s0 = s0 > 0.f ? s0 : expm1f(s0);
    s1 = s1 > 0.f ? s1 : expm1f(s1);

    // neigh half (cols 128..255): 8-deep pipelined gather
    float a0 = 0.f, a1 = 0.f;
    const int mm = (m + 7) & ~7;
    for (int e0 = 0; e0 < mm; e0 += 8) {
        GATHER(0) GATHER(1) GATHER(2) GATHER(3)
        GATHER(4) GATHER(5) GATHER(6) GATHER(7)
        ACCUM(0) ACCUM(1) ACCUM(2) ACCUM(3)
        ACCUM(4) ACCUM(5) ACCUM(6) ACCUM(7)
    }
    a0 += bw[lane * 2];
    a1 += bw[lane * 2 + 1];
    a0 = a0 > 0.f ? a0 : expm1f(a0);
    a1 = a1 > 0.f ? a1 : expm1f(a1);

    // layernorm over 256 values (4 per lane)
    float s  = s0 + s1 + a0 + a1;
    float s2 = s0 * s0 + s1 * s1 + a0 * a0 + a1 * a1;
    #pragma unroll
    for (int o = 32; o > 0; o >>= 1) {
        s  += __shfl_xor(s,  o, 64);
        s2 += __shfl_xor(s2, o, 64);
    }
    float mean = s * (1.f / 256.f);
    float var  = s2 * (1.f / 256.f) - mean * mean;
    float rstd = rsqrtf(var + 1e-9f);

    float* orow = out + (long)row * 256;
    float2 w0, w1;
    w0.x = (s0 - mean) * rstd * scale[lane * 2]           + offs[lane * 2];
    w0.y = (s1 - mean) * rstd * scale[lane * 2 + 1]       + offs[lane * 2 + 1];
    w1.x = (a0 - mean) * rstd * scale[128 + lane * 2]     + offs[128 + lane * 2];
    w1.y = (a1 - mean) * rstd * scale[128 + lane * 2 + 1] + offs[128 + lane * 2 + 1];
    *(float2*)(orow + lane * 2)       = w0;
    *(float2*)(orow + 128 + lane * 2) = w1;
}

extern "C" void kernel_launch(void* const* d_in, const int* in_sizes, int n_in,
                              void* d_out, int out_size, void* d_ws, size_t ws_size,
                              hipStream_t stream) {
    const float* x     = (const float*)d_in[0];
    const int*   erows = (const int*)  d_in[1];
    const int*   ecols = (const int*)  d_in[2];
    const float* evals = (const float*)d_in[3];
    const int*   sn    = (const int*)  d_in[4];
    const float* Ww    = (const float*)d_in[5];
    const float* bw    = (const float*)d_in[6];
    const float* Wb    = (const float*)d_in[7];
    const float* bb    = (const float*)d_in[8];
    const float* scale = (const float*)d_in[9];
    const float* offs  = (const float*)d_in[10];
    float* out = (float*)d_out;

    char* ws = (char*)d_ws;
    int*   cnt     = (int*)  (ws + WS_CNT);
    unsigned short* Wtw   = (unsigned short*)(ws + WS_WTW);
    unsigned short* Wtb   = (unsigned short*)(ws + WS_WTB);
    unsigned short* selfp = (unsigned short*)(ws + WS_SELF);
    unsigned short* ybuf  = (unsigned short*)(ws + WS_Y);
    int2*  csr_pad = (int2*) (ws + WS_CSR);

    k_init <<<256, 256, 0, stream>>>(Ww, Wb, Wtw, Wtb, cnt);
    k_mega <<<GSCAT + GBIG + GSELF, 256, 0, stream>>>(x, erows, ecols, evals, sn,
                                                      Wtw, Wtb, cnt, csr_pad, ybuf, selfp);
    k_sage <<<N_DST / 4, 256, 0, stream>>>(ybuf, selfp, cnt, csr_pad,
                                           bw, bb, scale, offs, out);
}